// Round 2
// baseline (21311.923 us; speedup 1.0000x reference)
//
#include <hip/hip_runtime.h>
#include <hip/hip_cooperative_groups.h>

namespace cg = cooperative_groups;

// Problem constants
#define BATCH   64
#define SEQT    512
#define NIN     512
#define NH      1024
#define NG      4096   // 4*NH

typedef __attribute__((ext_vector_type(8))) short short8;
typedef __attribute__((ext_vector_type(4))) float floatx4;

__device__ __forceinline__ float bf2f(unsigned short u) {
    union { float f; unsigned i; } v; v.i = ((unsigned)u) << 16; return v.f;
}
__device__ __forceinline__ unsigned short f2bf(float f) {
    union { float f; unsigned i; } v; v.f = f;
    unsigned x = v.i;
    unsigned r = (x + 0x7fffu + ((x >> 16) & 1u)) >> 16;  // RNE
    return (unsigned short)r;
}
__device__ __forceinline__ float sigm(float x) { return 1.0f / (1.0f + expf(-x)); }

// ---------------- prep kernels ----------------
__global__ void cvt_bf16(const float* __restrict__ src, unsigned short* __restrict__ dst, long n) {
    long i = (long)blockIdx.x * blockDim.x + threadIdx.x;
    long stride = (long)gridDim.x * blockDim.x;
    for (; i < n; i += stride) dst[i] = f2bf(src[i]);
}

// Rearrange W_hh (4096x1024 fp32) into per-block bf16 layout:
// dst[((j*16 + g*4 + nl) * 1024) + k] = W[(g*1024 + j*4 + nl)*1024 + k]
__global__ void prep_whh(const float* __restrict__ W, unsigned short* __restrict__ dst) {
    long i = (long)blockIdx.x * blockDim.x + threadIdx.x;
    if (i >= (long)NG * NH) return;
    int k = (int)(i & (NH - 1));
    int row = (int)(i >> 10);        // 0..4095
    int j = row >> 4, rr = row & 15;
    int g = rr >> 2, nl = rr & 3;
    long src = ((long)(g * NH + j * 4 + nl) << 10) + k;
    dst[i] = f2bf(W[src]);
}

// ---------------- precompute GEMM: G = x @ W_ih^T + b_ih + b_hh ----------------
__global__ __launch_bounds__(256) void gemm_ih(const unsigned short* __restrict__ A,
                                               const unsigned short* __restrict__ Wb,
                                               const float* __restrict__ b_ih,
                                               const float* __restrict__ b_hh,
                                               unsigned short* __restrict__ G) {
    __shared__ __align__(16) unsigned short a_lds[128][56];
    __shared__ __align__(16) unsigned short b_lds[128][56];
    const int tid  = threadIdx.x;
    const int lane = tid & 63;
    const int w    = tid >> 6;
    const int wm   = w >> 1, wn = w & 1;
    const int bm   = blockIdx.x, bn = blockIdx.y;

    floatx4 acc[4][4] = {};

    const int row = tid >> 1, seg = tid & 1;
    const unsigned short* gA = A  + ((size_t)(bm * 128 + row)) * NIN + seg * 16;
    const unsigned short* gB = Wb + ((size_t)(bn * 128 + row)) * NIN + seg * 16;

    for (int kt = 0; kt < 16; ++kt) {
        __syncthreads();
        *(uint4*)&a_lds[row][seg * 16]     = *(const uint4*)(gA + kt * 32);
        *(uint4*)&a_lds[row][seg * 16 + 8] = *(const uint4*)(gA + kt * 32 + 8);
        *(uint4*)&b_lds[row][seg * 16]     = *(const uint4*)(gB + kt * 32);
        *(uint4*)&b_lds[row][seg * 16 + 8] = *(const uint4*)(gB + kt * 32 + 8);
        __syncthreads();
        short8 af[4], bf[4];
#pragma unroll
        for (int mt = 0; mt < 4; ++mt)
            af[mt] = *(const short8*)&a_lds[wm * 64 + mt * 16 + (lane & 15)][(lane >> 4) * 8];
#pragma unroll
        for (int nt = 0; nt < 4; ++nt)
            bf[nt] = *(const short8*)&b_lds[wn * 64 + nt * 16 + (lane & 15)][(lane >> 4) * 8];
#pragma unroll
        for (int mt = 0; mt < 4; ++mt)
#pragma unroll
            for (int nt = 0; nt < 4; ++nt)
                acc[mt][nt] = __builtin_amdgcn_mfma_f32_16x16x32_bf16(af[mt], bf[nt], acc[mt][nt], 0, 0, 0);
    }
#pragma unroll
    for (int nt = 0; nt < 4; ++nt) {
        int n = bn * 128 + wn * 64 + nt * 16 + (lane & 15);
        float bias = b_ih[n] + b_hh[n];
#pragma unroll
        for (int mt = 0; mt < 4; ++mt) {
#pragma unroll
            for (int r = 0; r < 4; ++r) {
                int m = bm * 128 + wm * 64 + mt * 16 + (lane >> 4) * 4 + r;  // token
                int b = m >> 9, t = m & 511;
                size_t gi = ((size_t)(t * 64 + b)) * NG + n;
                G[gi] = f2bf(acc[mt][nt][r] + bias);
            }
        }
    }
}

// ---------------- lightweight grid barrier ----------------
// Monotonic-counter barrier. Release: every thread __threadfence() (drains
// stores; agent scope) + __syncthreads(); thread 0 atomically arrives and
// spins until all gridDim.x blocks of this phase arrived; acquire fence
// (invalidates this CU's L1 so other XCDs' hread writes are visible), then
// __syncthreads() releases the block.
__device__ __forceinline__ void grid_bar(unsigned* __restrict__ cnt, unsigned target, int nblk) {
    __threadfence();
    __syncthreads();
    if (threadIdx.x == 0) {
        __hip_atomic_fetch_add(cnt, 1u, __ATOMIC_RELEASE, __HIP_MEMORY_SCOPE_AGENT);
        while (__hip_atomic_load(cnt, __ATOMIC_RELAXED, __HIP_MEMORY_SCOPE_AGENT) < target)
            __builtin_amdgcn_s_sleep(1);
        __threadfence();  // acquire side: L1 invalidate
    }
    __syncthreads();
}

// ---------------- persistent sequential kernel ----------------
__global__ __launch_bounds__(256, 1) void seq_kernel(const unsigned short* __restrict__ Wp,
                                                     const unsigned short* __restrict__ G,
                                                     unsigned short* __restrict__ hread,
                                                     unsigned* __restrict__ bar,
                                                     float* __restrict__ out) {
    const int tid  = threadIdx.x;
    const int j    = blockIdx.x;
    const int lane = tid & 63;
    const int w    = tid >> 6;
    const int NBLK = gridDim.x;

    __shared__ __align__(16) unsigned short w_lds[16][1032];
    __shared__ float gates_lds[64][17];

    // Load W slice (16 rows x 1024) into LDS once.
    {
        const unsigned short* src = Wp + (size_t)j * 16 * NH;
        int r = tid >> 4, c0 = (tid & 15) * 64;
#pragma unroll
        for (int u = 0; u < 8; ++u)
            *(uint4*)&w_lds[r][c0 + u * 8] = *(const uint4*)(src + r * NH + c0 + u * 8);
    }
    // zero hread parity-0 buffer (65536 ushorts, exactly one per thread grid-wide)
    hread[(size_t)blockIdx.x * 256 + tid] = 0;

    const int cb = tid >> 2, nl = tid & 3;
    const int n  = j * 4 + nl;
    float h0 = 0.f, h1 = 0.f, h2 = 0.f, h3 = 0.f;
    float c0 = 0.f, c1 = 0.f, c2 = 0.f, c3 = 0.f;
    float c_read = 0.f;

    const unsigned short* Gp = G + (size_t)cb * NG + j * 4 + nl;
    const int kchunk = n >> 5, q = (n >> 3) & 3, jj = n & 7, mt = cb >> 4;
    const size_t wr_idx = ((size_t)((kchunk * 4 + mt) * 64 + (q * 16 + (cb & 15)))) * 8 + jj;
    float* out_h = out + ((size_t)cb * SEQT) * NH + n;

    const unsigned short* bBase = &w_lds[lane & 15][(lane >> 4) * 8];

    unsigned phase = 1;
    grid_bar(bar, phase * NBLK, NBLK); ++phase;

    for (int t = 0; t < SEQT; ++t) {
        // prefetch this thread's 4 input-projection gates (HBM) before the GEMM
        const unsigned short* Gt = Gp + (size_t)t * 64 * NG;
        unsigned short gi_u = Gt[0], gf_u = Gt[1024], gg_u = Gt[2048], go_u = Gt[3072];

        // GEMM: gates[64 x 16] = hread_h[64 x 1024] @ Wslice^T
        const unsigned short* aBase = hread + (size_t)(t & 1) * 65536 + ((size_t)w * 64 + lane) * 8;
        floatx4 acc[4] = {};
#pragma unroll
        for (int kk = 0; kk < 32; ++kk) {
            short8 a = *(const short8*)(aBase + (size_t)kk * 2048);
            short8 b = *(const short8*)(bBase + kk * 32);
            acc[kk & 3] = __builtin_amdgcn_mfma_f32_16x16x32_bf16(a, b, acc[kk & 3], 0, 0, 0);
        }
        floatx4 accv = (acc[0] + acc[1]) + (acc[2] + acc[3]);
#pragma unroll
        for (int r = 0; r < 4; ++r)
            gates_lds[w * 16 + (lane >> 4) * 4 + r][lane & 15] = accv[r];
        __syncthreads();

        // LSTM cell for (cb, n)
        float gi = gates_lds[cb][nl]      + bf2f(gi_u);
        float gf = gates_lds[cb][4 + nl]  + bf2f(gf_u);
        float gg = gates_lds[cb][8 + nl]  + bf2f(gg_u);
        float go = gates_lds[cb][12 + nl] + bf2f(go_u);

        float c = sigm(gf) * c_read + sigm(gi) * tanhf(gg);
        float h = sigm(go) * tanhf(c);

        out_h[(size_t)t * NH] = h;
        if (t == SEQT - 1) {
            float* o2 = out + (size_t)BATCH * SEQT * NH + (size_t)cb * 2 * NH;
            o2[n] = h;
            o2[NH + n] = c;
        }

        // shift ring, compute interpolated read state for step t+1
        h3 = h2; h2 = h1; h1 = h0; h0 = h;
        c3 = c2; c2 = c1; c1 = c0; c0 = c;
        float hr = 0.3125f * h0 + 0.9375f * h1 - 0.3125f * h2 + 0.0625f * h3;
        c_read   = 0.3125f * c0 + 0.9375f * c1 - 0.3125f * c2 + 0.0625f * c3;
        hread[(size_t)((t + 1) & 1) * 65536 + wr_idx] = f2bf(hr);

        grid_bar(bar, phase * NBLK, NBLK); ++phase;
    }
}

// ---------------- host ----------------
extern "C" void kernel_launch(void* const* d_in, const int* in_sizes, int n_in,
                              void* d_out, int out_size, void* d_ws, size_t ws_size,
                              hipStream_t stream) {
    const float* x    = (const float*)d_in[0];
    const float* Wih  = (const float*)d_in[1];
    const float* Whh  = (const float*)d_in[2];
    const float* bih  = (const float*)d_in[3];
    const float* bhh  = (const float*)d_in[4];
    float* outp = (float*)d_out;

    char* ws = (char*)d_ws;
    unsigned short* xb    = (unsigned short*)(ws);                 // 33,554,432 B
    unsigned short* wihb  = (unsigned short*)(ws + 33554432);      //  4,194,304 B
    unsigned short* whhb  = (unsigned short*)(ws + 37748736);      //  8,388,608 B
    unsigned short* G     = (unsigned short*)(ws + 46137344);      // 268,435,456 B
    unsigned short* hread = (unsigned short*)(ws + 314572800);     //    262,144 B
    unsigned*       bar   = (unsigned*)(ws + 314834944);           //        128 B

    hipMemsetAsync(bar, 0, 128, stream);
    cvt_bf16<<<4096, 256, 0, stream>>>(x, xb, (long)BATCH * SEQT * NIN);
    cvt_bf16<<<2048, 256, 0, stream>>>(Wih, wihb, (long)NG * NIN);
    prep_whh<<<16384, 256, 0, stream>>>(Whh, whhb);
    gemm_ih<<<dim3(256, 32), 256, 0, stream>>>(xb, wihb, bih, bhh, G);

    void* args[] = { (void*)&whhb, (void*)&G, (void*)&hread, (void*)&bar, (void*)&outp };
    hipLaunchCooperativeKernel((void*)seq_kernel, dim3(256), dim3(256), args, 0, stream);
}

// Round 3
// 3480.954 us; speedup vs baseline: 6.1224x; 6.1224x over previous
//
#include <hip/hip_runtime.h>

// Problem constants
#define BATCH   64
#define SEQT    512
#define NIN     512
#define NH      1024
#define NG      4096   // 4*NH

typedef __attribute__((ext_vector_type(8))) short short8;
typedef __attribute__((ext_vector_type(4))) float floatx4;

__device__ __forceinline__ float bf2f(unsigned short u) {
    union { float f; unsigned i; } v; v.i = ((unsigned)u) << 16; return v.f;
}
__device__ __forceinline__ unsigned short f2bf(float f) {
    union { float f; unsigned i; } v; v.f = f;
    unsigned x = v.i;
    unsigned r = (x + 0x7fffu + ((x >> 16) & 1u)) >> 16;  // RNE
    return (unsigned short)r;
}
__device__ __forceinline__ float sigm(float x) { return 1.0f / (1.0f + expf(-x)); }

// ---------------- prep kernels ----------------
__global__ void cvt_bf16(const float* __restrict__ src, unsigned short* __restrict__ dst, long n) {
    long i = (long)blockIdx.x * blockDim.x + threadIdx.x;
    long stride = (long)gridDim.x * blockDim.x;
    for (; i < n; i += stride) dst[i] = f2bf(src[i]);
}

// Rearrange W_hh (4096x1024 fp32) into per-block bf16 layout:
// dst[((j*16 + g*4 + nl) * 1024) + k] = W[(g*1024 + j*4 + nl)*1024 + k]
__global__ void prep_whh(const float* __restrict__ W, unsigned short* __restrict__ dst) {
    long i = (long)blockIdx.x * blockDim.x + threadIdx.x;
    if (i >= (long)NG * NH) return;
    int k = (int)(i & (NH - 1));
    int row = (int)(i >> 10);        // 0..4095
    int j = row >> 4, rr = row & 15;
    int g = rr >> 2, nl = rr & 3;
    long src = ((long)(g * NH + j * 4 + nl) << 10) + k;
    dst[i] = f2bf(W[src]);
}

// ---------------- precompute GEMM: G = x @ W_ih^T + b_ih + b_hh ----------------
__global__ __launch_bounds__(256) void gemm_ih(const unsigned short* __restrict__ A,
                                               const unsigned short* __restrict__ Wb,
                                               const float* __restrict__ b_ih,
                                               const float* __restrict__ b_hh,
                                               unsigned short* __restrict__ G) {
    __shared__ __align__(16) unsigned short a_lds[128][56];
    __shared__ __align__(16) unsigned short b_lds[128][56];
    const int tid  = threadIdx.x;
    const int lane = tid & 63;
    const int w    = tid >> 6;
    const int wm   = w >> 1, wn = w & 1;
    const int bm   = blockIdx.x, bn = blockIdx.y;

    floatx4 acc[4][4] = {};

    const int row = tid >> 1, seg = tid & 1;
    const unsigned short* gA = A  + ((size_t)(bm * 128 + row)) * NIN + seg * 16;
    const unsigned short* gB = Wb + ((size_t)(bn * 128 + row)) * NIN + seg * 16;

    for (int kt = 0; kt < 16; ++kt) {
        __syncthreads();
        *(uint4*)&a_lds[row][seg * 16]     = *(const uint4*)(gA + kt * 32);
        *(uint4*)&a_lds[row][seg * 16 + 8] = *(const uint4*)(gA + kt * 32 + 8);
        *(uint4*)&b_lds[row][seg * 16]     = *(const uint4*)(gB + kt * 32);
        *(uint4*)&b_lds[row][seg * 16 + 8] = *(const uint4*)(gB + kt * 32 + 8);
        __syncthreads();
        short8 af[4], bf[4];
#pragma unroll
        for (int mt = 0; mt < 4; ++mt)
            af[mt] = *(const short8*)&a_lds[wm * 64 + mt * 16 + (lane & 15)][(lane >> 4) * 8];
#pragma unroll
        for (int nt = 0; nt < 4; ++nt)
            bf[nt] = *(const short8*)&b_lds[wn * 64 + nt * 16 + (lane & 15)][(lane >> 4) * 8];
#pragma unroll
        for (int mt = 0; mt < 4; ++mt)
#pragma unroll
            for (int nt = 0; nt < 4; ++nt)
                acc[mt][nt] = __builtin_amdgcn_mfma_f32_16x16x32_bf16(af[mt], bf[nt], acc[mt][nt], 0, 0, 0);
    }
#pragma unroll
    for (int nt = 0; nt < 4; ++nt) {
        int n = bn * 128 + wn * 64 + nt * 16 + (lane & 15);
        float bias = b_ih[n] + b_hh[n];
#pragma unroll
        for (int mt = 0; mt < 4; ++mt) {
#pragma unroll
            for (int r = 0; r < 4; ++r) {
                int m = bm * 128 + wm * 64 + mt * 16 + (lane >> 4) * 4 + r;  // token
                int b = m >> 9, t = m & 511;
                size_t gi = ((size_t)(t * 64 + b)) * NG + n;
                G[gi] = f2bf(acc[mt][nt][r] + bias);
            }
        }
    }
}

// ---------------- persistent sequential kernel ----------------
// Flag-based producer/consumer sync, no global barrier:
//  - hread writes: agent-scope write-through 4B atomic stores (no dirty L2)
//  - flags[j] = t+1 published by relaxed agent store after __syncthreads'
//    vmcnt(0) drain (scoped stores ack at LLC)
//  - consumers: thread i polls flags[i] (parallel, no RMW contention), then
//    wave0-only agent acquire fence (buffer_inv; L1 per-CU, L2 per-XCD)
__global__ __launch_bounds__(256, 1) void seq_kernel(const unsigned short* __restrict__ Wp,
                                                     const unsigned short* __restrict__ G,
                                                     unsigned short* __restrict__ hread,
                                                     unsigned* __restrict__ flags,
                                                     float* __restrict__ out) {
    const int tid  = threadIdx.x;
    const int j    = blockIdx.x;
    const int lane = tid & 63;
    const int w    = tid >> 6;

    __shared__ __align__(16) unsigned short w_lds[16][1032];
    __shared__ float gates_lds[64][17];

    // Load W slice (16 rows x 1024) into LDS once.
    {
        const unsigned short* src = Wp + (size_t)j * 16 * NH;
        int r = tid >> 4, c0 = (tid & 15) * 64;
#pragma unroll
        for (int u = 0; u < 8; ++u)
            *(uint4*)&w_lds[r][c0 + u * 8] = *(const uint4*)(src + r * NH + c0 + u * 8);
    }
    __syncthreads();

    const int cb = tid >> 2, nl = tid & 3;
    const int n  = j * 4 + nl;
    float h0 = 0.f, h1 = 0.f, h2 = 0.f, h3 = 0.f;
    float c0 = 0.f, c1 = 0.f, c2 = 0.f, c3 = 0.f;
    float c_read = 0.f;

    const unsigned short* Gp = G + (size_t)cb * NG + j * 4 + nl;
    const int kchunk = n >> 5, q = (n >> 3) & 3, jj = n & 7, mt = cb >> 4;
    const size_t wr_idx = ((size_t)((kchunk * 4 + mt) * 64 + (q * 16 + (cb & 15)))) * 8 + jj;
    float* out_h = out + ((size_t)cb * SEQT) * NH + n;

    const unsigned short* bBase = &w_lds[lane & 15][(lane >> 4) * 8];

    for (int t = 0; t < SEQT; ++t) {
        // prefetch this thread's 4 input-projection gates (HBM) before the wait
        const unsigned short* Gt = Gp + (size_t)t * 64 * NG;
        unsigned short gi_u = Gt[0], gf_u = Gt[1024], gg_u = Gt[2048], go_u = Gt[3072];

        if (t > 0) {
            // wait for all producers of step-t data (thread i watches block i)
            unsigned tgt = (unsigned)t;
            while (__hip_atomic_load(&flags[tid], __ATOMIC_RELAXED, __HIP_MEMORY_SCOPE_AGENT) < tgt)
                __builtin_amdgcn_s_sleep(1);
            __syncthreads();
            if (w == 0) __builtin_amdgcn_fence(__ATOMIC_ACQUIRE, "agent");  // buffer_inv: L1 + per-XCD L2
            __syncthreads();
        }

        // GEMM: gates[64 x 16] = hread_h[64 x 1024] @ Wslice^T
        const unsigned short* aBase = hread + (size_t)(t & 1) * 65536 + ((size_t)w * 64 + lane) * 8;
        floatx4 acc[4] = {};
#pragma unroll
        for (int kk = 0; kk < 32; ++kk) {
            short8 a = *(const short8*)(aBase + (size_t)kk * 2048);
            short8 b = *(const short8*)(bBase + kk * 32);
            acc[kk & 3] = __builtin_amdgcn_mfma_f32_16x16x32_bf16(a, b, acc[kk & 3], 0, 0, 0);
        }
        floatx4 accv = (acc[0] + acc[1]) + (acc[2] + acc[3]);
#pragma unroll
        for (int r = 0; r < 4; ++r)
            gates_lds[w * 16 + (lane >> 4) * 4 + r][lane & 15] = accv[r];
        __syncthreads();

        // LSTM cell for (cb, n)
        float gi = gates_lds[cb][nl]      + bf2f(gi_u);
        float gf = gates_lds[cb][4 + nl]  + bf2f(gf_u);
        float gg = gates_lds[cb][8 + nl]  + bf2f(gg_u);
        float go = gates_lds[cb][12 + nl] + bf2f(go_u);

        float c = sigm(gf) * c_read + sigm(gi) * tanhf(gg);
        float h = sigm(go) * tanhf(c);

        out_h[(size_t)t * NH] = h;
        if (t == SEQT - 1) {
            float* o2 = out + (size_t)BATCH * SEQT * NH + (size_t)cb * 2 * NH;
            o2[n] = h;
            o2[NH + n] = c;
        }

        // shift ring, compute interpolated read state for step t+1
        h3 = h2; h2 = h1; h1 = h0; h0 = h;
        c3 = c2; c2 = c1; c1 = c0; c0 = c;
        float hr = 0.3125f * h0 + 0.9375f * h1 - 0.3125f * h2 + 0.0625f * h3;
        c_read   = 0.3125f * c0 + 0.9375f * c1 - 0.3125f * c2 + 0.0625f * c3;

        // publish hr (bf16) via agent-scope write-through store; pair the two
        // adjacent 2B values (jj, jj^1 are neighbors) into one 4B store
        {
            unsigned val  = (unsigned)f2bf(hr);
            unsigned part = __shfl_xor(val, 1);
            if ((tid & 1) == 0) {
                unsigned word = val | (part << 16);
                unsigned* dst = (unsigned*)(hread + (size_t)((t + 1) & 1) * 65536 + wr_idx);
                __hip_atomic_store(dst, word, __ATOMIC_RELAXED, __HIP_MEMORY_SCOPE_AGENT);
            }
        }

        __syncthreads();  // drains vmcnt(0): all scoped stores of this block are at LLC
        if (tid == 0)
            __hip_atomic_store(&flags[j], (unsigned)(t + 1), __ATOMIC_RELAXED, __HIP_MEMORY_SCOPE_AGENT);
    }
}

// ---------------- host ----------------
extern "C" void kernel_launch(void* const* d_in, const int* in_sizes, int n_in,
                              void* d_out, int out_size, void* d_ws, size_t ws_size,
                              hipStream_t stream) {
    const float* x    = (const float*)d_in[0];
    const float* Wih  = (const float*)d_in[1];
    const float* Whh  = (const float*)d_in[2];
    const float* bih  = (const float*)d_in[3];
    const float* bhh  = (const float*)d_in[4];
    float* outp = (float*)d_out;

    char* ws = (char*)d_ws;
    unsigned short* xb    = (unsigned short*)(ws);                 // 33,554,432 B
    unsigned short* wihb  = (unsigned short*)(ws + 33554432);      //  4,194,304 B
    unsigned short* whhb  = (unsigned short*)(ws + 37748736);      //  8,388,608 B
    unsigned short* G     = (unsigned short*)(ws + 46137344);      // 268,435,456 B
    unsigned short* hread = (unsigned short*)(ws + 314572800);     //    262,144 B
    unsigned*       flags = (unsigned*)(ws + 314834944);           //      1,024 B

    // zero hread (step-0 state) and flags; visible to seq_kernel via dispatch boundary
    hipMemsetAsync(hread, 0, 262144 + 1024 + (314834944 - 314572800 - 262144), stream);

    cvt_bf16<<<4096, 256, 0, stream>>>(x, xb, (long)BATCH * SEQT * NIN);
    cvt_bf16<<<2048, 256, 0, stream>>>(Wih, wihb, (long)NG * NIN);
    prep_whh<<<16384, 256, 0, stream>>>(Whh, whhb);
    gemm_ih<<<dim3(256, 32), 256, 0, stream>>>(xb, wihb, bih, bhh, G);

    void* args[] = { (void*)&whhb, (void*)&G, (void*)&hread, (void*)&flags, (void*)&outp };
    hipLaunchCooperativeKernel((void*)seq_kernel, dim3(256), dim3(256), args, 0, stream);
}